// Round 3
// baseline (17402.989 us; speedup 1.0000x reference)
//
#include <hip/hip_runtime.h>

// BiLSTM tagger, MI355X. Round 3: k_recurrent rebuilt barrier-free + VGPR-pinned weights.
//  - Round-2 counters showed VGPR_Count=96: compiler sank the Whh loads into the step
//    loop (re-streamed 512B/lane/step from L2). Fix: asm volatile("" : "+v") pins.
//  - Lane (ru,ke) owns ALL 4 gate rows (i,f,g,o) of unit u=wave*8+ru over k-slice ke*32..+32.
//    Butterfly shfl_xor gives every lane the full sums -> ke<4 lanes each do one activation,
//    3 shfl gather, ke==0 does c/h. No gacc, no __syncthreads.
//  - Per-wave private h_sh copy; each wave redundantly polls the tagged exchange. Waves are
//    fully independent actors (skew-safe: slot (s&1) overwrite needs tags s+2 everywhere,
//    which implies every wave finished reading slot s&1 — 2-buffer parity still safe).
//  - pregates layout changed to [dir][t][unit*4+gate] so per-lane pregate = 1 scalar load.
//
// Workspace (d_ws) ~92.5 MB: same map as round 2.

#define S_LEN 8192
#define LC    16
#define DW    256
#define DC    64
#define HC    128
#define H2    256
#define NG    1024   // 4*H2
#define NTAG  64
#define CV    128

__device__ __forceinline__ float sigmoid_f(float x){
  return __frcp_rn(1.0f + __expf(-x));
}
__device__ __forceinline__ float tanh_f(float x){
  float a = fabsf(x);
  float t = 1.0f - 2.0f * __frcp_rn(__expf(2.0f*a) + 1.0f);
  return copysignf(t, x);
}

// ---------------------------------------------------------------- k_prep
__global__ __launch_bounds__(512) void k_prep(
    const float* __restrict__ char_emb, const float* __restrict__ char_Wih,
    const float* __restrict__ char_Whh, const float* __restrict__ char_b,
    float* __restrict__ preC, float* __restrict__ whhTc)
{
  int blk = blockIdx.x, tid = threadIdx.x;
  __shared__ float esh[DC];
  if (blk < CV){
    if (tid < DC) esh[tid] = char_emb[blk*DC + tid];
    __syncthreads();
    const float* wr = char_Wih + (size_t)tid*DC;
    float acc = char_b[tid];
#pragma unroll
    for (int d=0; d<DC; d+=4){
      float4 wv = *(const float4*)&wr[d];
      acc += wv.x*esh[d] + wv.y*esh[d+1] + wv.z*esh[d+2] + wv.w*esh[d+3];
    }
    preC[(size_t)blk*512 + tid] = acc;
  } else {
    int k = blk - CV;
    whhTc[(size_t)k*512 + tid] = char_Whh[(size_t)tid*HC + k];
  }
}

// ---------------------------------------------------------------- k_char_lstm
__global__ __launch_bounds__(256) void k_char_lstm(
    const int* __restrict__ charsets, const int* __restrict__ lengths,
    const float* __restrict__ preC, const float* __restrict__ whhTc,
    float* __restrict__ embeds)
{
  int blk = blockIdx.x, tid = threadIdx.x;
  int s0 = blk*16;
  __shared__ float h_sh[16][132];
  __shared__ float gsh[512][17];
  __shared__ int   ch_sh[16];

  for (int i = tid; i < 16*132; i += 256) (&h_sh[0][0])[i] = 0.0f;

  int uw  = tid & 15;
  int ujg = tid >> 4;
  float c[8];
#pragma unroll
  for (int u=0; u<8; u++) c[u] = 0.0f;
  int lw = lengths[s0 + uw];

  int g0 = tid, g1 = tid + 256;
  __syncthreads();

  for (int t=0; t<LC; t++){
    if (tid < 16) ch_sh[tid] = charsets[(size_t)(s0+tid)*LC + t];
    __syncthreads();                                        // (A)

    float acc0[16], acc1[16];
#pragma unroll
    for (int w=0; w<16; w++){
      int ch = ch_sh[w];
      acc0[w] = preC[(size_t)ch*512 + g0];
      acc1[w] = preC[(size_t)ch*512 + g1];
    }
    for (int k4=0; k4<HC; k4+=4){
      float w00 = whhTc[(size_t)(k4+0)*512 + g0];
      float w01 = whhTc[(size_t)(k4+1)*512 + g0];
      float w02 = whhTc[(size_t)(k4+2)*512 + g0];
      float w03 = whhTc[(size_t)(k4+3)*512 + g0];
      float w10 = whhTc[(size_t)(k4+0)*512 + g1];
      float w11 = whhTc[(size_t)(k4+1)*512 + g1];
      float w12 = whhTc[(size_t)(k4+2)*512 + g1];
      float w13 = whhTc[(size_t)(k4+3)*512 + g1];
#pragma unroll
      for (int w=0; w<16; w++){
        float4 h4 = *(const float4*)&h_sh[w][k4];
        acc0[w] += w00*h4.x + w01*h4.y + w02*h4.z + w03*h4.w;
        acc1[w] += w10*h4.x + w11*h4.y + w12*h4.z + w13*h4.w;
      }
    }
#pragma unroll
    for (int w=0; w<16; w++){ gsh[g0][w] = acc0[w]; gsh[g1][w] = acc1[w]; }
    __syncthreads();                                        // (G)

    float hnew[8];
#pragma unroll
    for (int u=0; u<8; u++){
      int j = ujg*8 + u;
      float gi = sigmoid_f(gsh[j][uw]);
      float gf = sigmoid_f(gsh[HC + j][uw]);
      float gg = tanh_f   (gsh[2*HC + j][uw]);
      float go = sigmoid_f(gsh[3*HC + j][uw]);
      c[u] = gf*c[u] + gi*gg;
      hnew[u] = go * tanh_f(c[u]);
    }
#pragma unroll
    for (int u=0; u<8; u+=4)
      *(float4*)&h_sh[uw][ujg*8 + u] = make_float4(hnew[u],hnew[u+1],hnew[u+2],hnew[u+3]);
    if (t == lw-1){
#pragma unroll
      for (int u=0; u<8; u+=4)
        *(float4*)&embeds[(size_t)(s0+uw)*384 + ujg*8 + u]
            = make_float4(hnew[u],hnew[u+1],hnew[u+2],hnew[u+3]);
    }
  }
}

// ---------------------------------------------------------------- k_gather
__global__ __launch_bounds__(256) void k_gather(
    const int* __restrict__ sentence, const float* __restrict__ word_emb,
    float* __restrict__ embeds)
{
  int blk = blockIdx.x, tid = threadIdx.x;
  int s = blk*8 + (tid >> 5);
  int lane = tid & 31;
  int idx = sentence[s];
  const float4* src = (const float4*)(word_emb + (size_t)idx*DW);
  float4* dst = (float4*)(embeds + (size_t)s*384 + 128);
  dst[lane]      = src[lane];
  dst[lane + 32] = src[lane + 32];
}

// ---------------------------------------------------------------- k_pregate
// NEW output layout: pregates[dir][t][unit*4 + gate]  (unit = n&255, gate = n>>8)
__global__ __launch_bounds__(256) void k_pregate(
    const float* __restrict__ embeds,
    const float* __restrict__ Wih_fw, const float* __restrict__ b_fw,
    const float* __restrict__ Wih_bw, const float* __restrict__ b_bw,
    float* __restrict__ pregates)
{
  int dir = blockIdx.z;
  const float* W    = dir ? Wih_bw : Wih_fw;
  const float* bias = dir ? b_bw   : b_fw;
  int t0 = blockIdx.x*64, n0 = blockIdx.y*64;
  __shared__ float a_sh[16][68];
  __shared__ float b_sh[16][68];
  int tid = threadIdx.x;
  int li = tid & 63, kq = tid >> 6;
  int ti = tid >> 4, tj = tid & 15;
  float acc[4][4];
#pragma unroll
  for (int ii=0; ii<4; ii++)
#pragma unroll
    for (int jj=0; jj<4; jj++) acc[ii][jj] = 0.0f;

  for (int k0=0; k0<384; k0+=16){
    float4 av = *(const float4*)&embeds[(size_t)(t0+li)*384 + k0 + kq*4];
    float4 bv = *(const float4*)&W     [(size_t)(n0+li)*384 + k0 + kq*4];
    __syncthreads();
    a_sh[kq*4+0][li]=av.x; a_sh[kq*4+1][li]=av.y; a_sh[kq*4+2][li]=av.z; a_sh[kq*4+3][li]=av.w;
    b_sh[kq*4+0][li]=bv.x; b_sh[kq*4+1][li]=bv.y; b_sh[kq*4+2][li]=bv.z; b_sh[kq*4+3][li]=bv.w;
    __syncthreads();
#pragma unroll
    for (int kk=0; kk<16; kk++){
      float4 a4 = *(const float4*)&a_sh[kk][ti*4];
      float4 b4 = *(const float4*)&b_sh[kk][tj*4];
      float aa[4] = {a4.x,a4.y,a4.z,a4.w};
      float bb[4] = {b4.x,b4.y,b4.z,b4.w};
#pragma unroll
      for (int ii=0; ii<4; ii++)
#pragma unroll
        for (int jj=0; jj<4; jj++) acc[ii][jj] += aa[ii]*bb[jj];
    }
  }
  float4 bias4 = *(const float4*)&bias[n0 + tj*4];
  float bb2[4] = {bias4.x,bias4.y,bias4.z,bias4.w};
  int q = n0 >> 8;                       // gate block, constant per blockIdx.y
  int jb = (n0 & 255) + tj*4;            // unit index base
#pragma unroll
  for (int ii=0; ii<4; ii++){
    size_t rowoff = ((size_t)dir*S_LEN + (t0+ti*4+ii))*NG;
#pragma unroll
    for (int jj=0; jj<4; jj++)
      pregates[rowoff + (size_t)(jb+jj)*4 + q] = acc[ii][jj] + bb2[jj];
  }
}

// ---------------------------------------------------------------- k_recurrent
// 64 blocks; workers b%8==0 (fw) / b%8==1 (bw), slice g=b>>3 owns units [32g,32g+32).
// Lane (ru=lane>>3, ke=lane&7) of wave w: unit u = w*8+ru, gate rows i,f,g,o of u,
// k-slice [32ke,32ke+32). Weights pinned in VGPRs via empty asm. No __syncthreads:
// per-wave h_sh copies, every wave polls the tagged u64 exchange itself.
__global__ __launch_bounds__(256, 1) void k_recurrent(
    const float* __restrict__ Whh_fw, const float* __restrict__ Whh_bw,
    const float* __restrict__ pregates,
    unsigned long long* hbuf,
    float* __restrict__ hout)
{
  int b = blockIdx.x;
  if ((b & 7) > 1) return;
  int dir = b & 7, g = b >> 3;
  int tid = threadIdx.x;
  int wave = tid >> 6, lane = tid & 63;
  int ru = lane >> 3, ke = lane & 7;
  int ul = wave*8 + ru;                // unit-local 0..31
  int j  = g*32 + ul;                  // global h-unit 0..255
  const float* Whh = dir ? Whh_bw : Whh_fw;
  const float* pgb = pregates + (size_t)dir * S_LEN * NG;
  unsigned long long* hb = hbuf + (size_t)dir * 2 * H2;

  __shared__ float h_sh[4][8*36];      // per-wave private padded h copies

  // w[q][kk] = Whh[(q*256 + j)*256 + ke*32 + kk]
  float w[4][32];
#pragma unroll
  for (int q=0; q<4; q++){
    const float* wr = Whh + ((size_t)(q*H2 + j))*H2 + ke*32;
#pragma unroll
    for (int kq=0; kq<8; kq++){
      float4 v = *(const float4*)&wr[kq*4];
      w[q][kq*4+0]=v.x; w[q][kq*4+1]=v.y; w[q][kq*4+2]=v.z; w[q][kq*4+3]=v.w;
    }
  }
#pragma unroll
  for (int q=0; q<4; q++)
#pragma unroll
    for (int kk=0; kk<32; kk++)
      asm volatile("" : "+v"(w[q][kk]));   // pin: forbid re-load inside step loop

  // init own-wave h to zero (k = lane + 64m)
#pragma unroll
  for (int m=0; m<4; m++){
    int k = lane + 64*m;
    h_sh[wave][(k>>5)*36 + (k&31)] = 0.0f;
  }
  float c = 0.0f;

  int t0 = dir ? (S_LEN-1) : 0;
  float pgv = (ke < 4) ? pgb[(size_t)t0*NG + j*4 + ke] : 0.0f;

  for (int s=0; s<S_LEN; s++){
    int t = dir ? (S_LEN-1-s) : s;

    float a0=0.f, a1=0.f, a2=0.f, a3=0.f;
    const float* hk = &h_sh[wave][ke*36];
#pragma unroll
    for (int kq=0; kq<8; kq++){
      float4 h4 = *(const float4*)&hk[kq*4];
      a0 += w[0][kq*4+0]*h4.x + w[0][kq*4+1]*h4.y + w[0][kq*4+2]*h4.z + w[0][kq*4+3]*h4.w;
      a1 += w[1][kq*4+0]*h4.x + w[1][kq*4+1]*h4.y + w[1][kq*4+2]*h4.z + w[1][kq*4+3]*h4.w;
      a2 += w[2][kq*4+0]*h4.x + w[2][kq*4+1]*h4.y + w[2][kq*4+2]*h4.z + w[2][kq*4+3]*h4.w;
      a3 += w[3][kq*4+0]*h4.x + w[3][kq*4+1]*h4.y + w[3][kq*4+2]*h4.z + w[3][kq*4+3]*h4.w;
    }
    // butterfly over ke bits: all 8 lanes of the group end with full 256-k sums
    a0 += __shfl_xor(a0,1); a1 += __shfl_xor(a1,1); a2 += __shfl_xor(a2,1); a3 += __shfl_xor(a3,1);
    a0 += __shfl_xor(a0,2); a1 += __shfl_xor(a1,2); a2 += __shfl_xor(a2,2); a3 += __shfl_xor(a3,2);
    a0 += __shfl_xor(a0,4); a1 += __shfl_xor(a1,4); a2 += __shfl_xor(a2,4); a3 += __shfl_xor(a3,4);

    // lane ke<4 computes activation of gate ke (i,f,g,o); g uses tanh = 2*sig(2x)-1
    float x  = (ke==0) ? a0 : (ke==1) ? a1 : (ke==2) ? a2 : a3;
    x += pgv;
    float xx  = (ke==2) ? (x + x) : x;
    float sg  = sigmoid_f(xx);
    float act = (ke==2) ? (sg + sg - 1.0f) : sg;
    int basel = lane & ~7;
    float fA = __shfl(act, basel+1);
    float gA = __shfl(act, basel+2);
    float oA = __shfl(act, basel+3);
    if (ke == 0){
      c = fA*c + act*gA;
      float hn = oA * tanh_f(c);
      unsigned long long pack =
          ((unsigned long long)__float_as_uint(hn) << 32) | (unsigned long long)(unsigned)(s+1);
      __hip_atomic_store(&hb[(s&1)*H2 + j], pack,
                         __ATOMIC_RELAXED, __HIP_MEMORY_SCOPE_AGENT);
      hout[(size_t)t*512 + dir*H2 + j] = hn;
    }
    if (ke < 4 && s+1 < S_LEN){
      int tn = dir ? (S_LEN-2-s) : (s+1);
      pgv = pgb[(size_t)tn*NG + j*4 + ke];
    }
    if (s+1 < S_LEN){
      unsigned tag = (unsigned)(s+1);
      unsigned long long* base2 = &hb[(s&1)*H2];
      unsigned long long v0,v1,v2,v3;
      for (;;){
        v0 = __hip_atomic_load(base2+lane,     __ATOMIC_RELAXED, __HIP_MEMORY_SCOPE_AGENT);
        v1 = __hip_atomic_load(base2+lane+64,  __ATOMIC_RELAXED, __HIP_MEMORY_SCOPE_AGENT);
        v2 = __hip_atomic_load(base2+lane+128, __ATOMIC_RELAXED, __HIP_MEMORY_SCOPE_AGENT);
        v3 = __hip_atomic_load(base2+lane+192, __ATOMIC_RELAXED, __HIP_MEMORY_SCOPE_AGENT);
        if ( ((unsigned)v0==tag) & ((unsigned)v1==tag) &
             ((unsigned)v2==tag) & ((unsigned)v3==tag) ) break;
      }
      int k0 = lane;
      h_sh[wave][((k0    )>>5)*36 + ((k0    )&31)] = __uint_as_float((unsigned)(v0>>32));
      h_sh[wave][((k0+ 64)>>5)*36 + ((k0+ 64)&31)] = __uint_as_float((unsigned)(v1>>32));
      h_sh[wave][((k0+128)>>5)*36 + ((k0+128)&31)] = __uint_as_float((unsigned)(v2>>32));
      h_sh[wave][((k0+192)>>5)*36 + ((k0+192)&31)] = __uint_as_float((unsigned)(v3>>32));
    }
  }
}

// ---------------------------------------------------------------- k_output
__global__ __launch_bounds__(256) void k_output(
    const float* __restrict__ hout, const float* __restrict__ outW,
    const float* __restrict__ outb, float* __restrict__ out)
{
  __shared__ float wT[128][66];
  __shared__ float hsh[32][132];
  __shared__ float lsh[32][66];
  __shared__ float msh[32][2];
  int t0 = blockIdx.x*32, tid = threadIdx.x;
  int n  = tid & 63, tg = tid >> 6;
  int sl = tid >> 3, kg = tid & 7;
  int wn = tid & 63, wk = tid >> 6;
  float acc[8];
#pragma unroll
  for (int u=0; u<8; u++) acc[u] = 0.0f;

  for (int kc=0; kc<4; kc++){
    int k0 = kc*128;
    float4 wreg[8];
#pragma unroll
    for (int e=0; e<8; e++) wreg[e] = *(const float4*)&outW[(size_t)wn*512 + k0 + wk*32 + e*4];
    float4 hreg[4];
#pragma unroll
    for (int e=0; e<4; e++) hreg[e] = *(const float4*)&hout[(size_t)(t0+sl)*512 + k0 + kg*16 + e*4];
    __syncthreads();
#pragma unroll
    for (int e=0; e<8; e++){
      int kk = wk*32 + e*4;
      wT[kk+0][wn]=wreg[e].x; wT[kk+1][wn]=wreg[e].y; wT[kk+2][wn]=wreg[e].z; wT[kk+3][wn]=wreg[e].w;
    }
#pragma unroll
    for (int e=0; e<4; e++) *(float4*)&hsh[sl][kg*16 + e*4] = hreg[e];
    __syncthreads();
#pragma unroll
    for (int kk4=0; kk4<128; kk4+=4){
      float w0 = wT[kk4+0][n], w1 = wT[kk4+1][n], w2 = wT[kk4+2][n], w3 = wT[kk4+3][n];
#pragma unroll
      for (int u=0; u<8; u++){
        float4 h4 = *(const float4*)&hsh[tg*8+u][kk4];
        acc[u] += w0*h4.x + w1*h4.y + w2*h4.z + w3*h4.w;
      }
    }
  }
  float bn = outb[n];
#pragma unroll
  for (int u=0; u<8; u++) lsh[tg*8+u][n] = acc[u] + bn;
  __syncthreads();
  if (tid < 32){
    float M = -3.4e38f;
    for (int j=0; j<NTAG; j++) M = fmaxf(M, lsh[tid][j]);
    float ssum = 0.0f;
    for (int j=0; j<NTAG; j++) ssum += expf(lsh[tid][j] - M);
    msh[tid][0] = M; msh[tid][1] = logf(ssum);
  }
  __syncthreads();
#pragma unroll
  for (int u=0; u<8; u++){
    int tt = tg*8+u;
    out[(size_t)(t0+tt)*NTAG + n] = lsh[tt][n] - msh[tt][0] - msh[tt][1];
  }
}

// ---------------------------------------------------------------- launch
extern "C" void kernel_launch(void* const* d_in, const int* in_sizes, int n_in,
                              void* d_out, int out_size, void* d_ws, size_t ws_size,
                              hipStream_t stream)
{
  (void)in_sizes; (void)n_in; (void)out_size; (void)ws_size;
  const int*   sentence = (const int*)d_in[0];
  const int*   charsets = (const int*)d_in[1];
  const int*   char_len = (const int*)d_in[2];
  const float* word_emb = (const float*)d_in[3];
  const float* char_emb = (const float*)d_in[4];
  const float* char_Wih = (const float*)d_in[5];
  const float* char_Whh = (const float*)d_in[6];
  const float* char_b   = (const float*)d_in[7];
  const float* fw_Wih   = (const float*)d_in[8];
  const float* fw_Whh   = (const float*)d_in[9];
  const float* fw_b     = (const float*)d_in[10];
  const float* bw_Wih   = (const float*)d_in[11];
  const float* bw_Whh   = (const float*)d_in[12];
  const float* bw_b     = (const float*)d_in[13];
  const float* out_W    = (const float*)d_in[14];
  const float* out_b    = (const float*)d_in[15];
  float* out = (float*)d_out;

  char* ws = (char*)d_ws;
  float* preC     = (float*)(ws);
  float* whhTc    = (float*)(ws + 262144);
  float* embeds   = (float*)(ws + 524288);
  float* pregates = (float*)(ws + 13107200);
  float* houtb    = (float*)(ws + 80216064);
  unsigned long long* hbuf = (unsigned long long*)(ws + 96993280);

  k_prep     <<<256,  512, 0, stream>>>(char_emb, char_Wih, char_Whh, char_b, preC, whhTc);
  k_char_lstm<<<512,  256, 0, stream>>>(charsets, char_len, preC, whhTc, embeds);
  k_gather   <<<1024, 256, 0, stream>>>(sentence, word_emb, embeds);
  k_pregate  <<<dim3(128,16,2), 256, 0, stream>>>(embeds, fw_Wih, fw_b, bw_Wih, bw_b, pregates);
  k_recurrent<<<64,   256, 0, stream>>>(fw_Whh, bw_Whh, pregates, hbuf, houtb);
  k_output   <<<256,  256, 0, stream>>>(houtb, out_W, out_b, out);
}

// Round 4
// 10813.919 us; speedup vs baseline: 1.6093x; 1.6093x over previous
//
#include <hip/hip_runtime.h>

// BiLSTM tagger, MI355X. Round 4: round-2 structure + the REAL weight-residency fix.
//  - ROOT CAUSE of rounds 1-3 weight re-streaming: hbuf lacked __restrict__, so the
//    in-loop atomic stores could alias Whh and the 128 weight loads were NOT hoistable.
//    Fixed: hbuf is __restrict__ -> LICM hoists, VGPRs hold the slice (expect ~200 VGPRs).
//  - Poll moved to wave 1 (overlaps wave 0's activation chain with poll issue).
//  - Single polling wave (round-3's all-wave redundant poll contended the coherence point).
//  - Fast __expf activations in both LSTM kernels.
//
// Workspace (d_ws) ~92.5 MB:
//   [0)          preC      256 KB
//   [262144)     whhTc     256 KB
//   [524288)     embeds    12 MB   [8192][384]
//   [13107200)   pregates  64 MB   [2][8192][1024]
//   [80216064)   hout      16 MB   [8192][512]  ([hf|hb])
//   [96993280)   hbuf      8 KB    [2][2][256] u64 tagged h (tag=step+1, poison-safe)

#define S_LEN 8192
#define LC    16
#define DW    256
#define DC    64
#define HC    128
#define H2    256
#define NG    1024   // 4*H2
#define NTAG  64
#define CV    128

__device__ __forceinline__ float sigmoid_f(float x){
  return __frcp_rn(1.0f + __expf(-x));
}
__device__ __forceinline__ float tanh_f(float x){
  float a = fabsf(x);
  float t = 1.0f - 2.0f * __frcp_rn(__expf(2.0f*a) + 1.0f);
  return copysignf(t, x);
}

// ---------------------------------------------------------------- k_prep
__global__ __launch_bounds__(512) void k_prep(
    const float* __restrict__ char_emb, const float* __restrict__ char_Wih,
    const float* __restrict__ char_Whh, const float* __restrict__ char_b,
    float* __restrict__ preC, float* __restrict__ whhTc)
{
  int blk = blockIdx.x, tid = threadIdx.x;
  __shared__ float esh[DC];
  if (blk < CV){
    if (tid < DC) esh[tid] = char_emb[blk*DC + tid];
    __syncthreads();
    const float* wr = char_Wih + (size_t)tid*DC;
    float acc = char_b[tid];
#pragma unroll
    for (int d=0; d<DC; d+=4){
      float4 wv = *(const float4*)&wr[d];
      acc += wv.x*esh[d] + wv.y*esh[d+1] + wv.z*esh[d+2] + wv.w*esh[d+3];
    }
    preC[(size_t)blk*512 + tid] = acc;
  } else {
    int k = blk - CV;
    whhTc[(size_t)k*512 + tid] = char_Whh[(size_t)tid*HC + k];
  }
}

// ---------------------------------------------------------------- k_char_lstm
__global__ __launch_bounds__(256) void k_char_lstm(
    const int* __restrict__ charsets, const int* __restrict__ lengths,
    const float* __restrict__ preC, const float* __restrict__ whhTc,
    float* __restrict__ embeds)
{
  int blk = blockIdx.x, tid = threadIdx.x;
  int s0 = blk*16;
  __shared__ float h_sh[16][132];
  __shared__ float gsh[512][17];
  __shared__ int   ch_sh[16];

  for (int i = tid; i < 16*132; i += 256) (&h_sh[0][0])[i] = 0.0f;

  int uw  = tid & 15;
  int ujg = tid >> 4;
  float c[8];
#pragma unroll
  for (int u=0; u<8; u++) c[u] = 0.0f;
  int lw = lengths[s0 + uw];

  int g0 = tid, g1 = tid + 256;
  __syncthreads();

  for (int t=0; t<LC; t++){
    if (tid < 16) ch_sh[tid] = charsets[(size_t)(s0+tid)*LC + t];
    __syncthreads();                                        // (A)

    float acc0[16], acc1[16];
#pragma unroll
    for (int w=0; w<16; w++){
      int ch = ch_sh[w];
      acc0[w] = preC[(size_t)ch*512 + g0];
      acc1[w] = preC[(size_t)ch*512 + g1];
    }
    for (int k4=0; k4<HC; k4+=4){
      float w00 = whhTc[(size_t)(k4+0)*512 + g0];
      float w01 = whhTc[(size_t)(k4+1)*512 + g0];
      float w02 = whhTc[(size_t)(k4+2)*512 + g0];
      float w03 = whhTc[(size_t)(k4+3)*512 + g0];
      float w10 = whhTc[(size_t)(k4+0)*512 + g1];
      float w11 = whhTc[(size_t)(k4+1)*512 + g1];
      float w12 = whhTc[(size_t)(k4+2)*512 + g1];
      float w13 = whhTc[(size_t)(k4+3)*512 + g1];
#pragma unroll
      for (int w=0; w<16; w++){
        float4 h4 = *(const float4*)&h_sh[w][k4];
        acc0[w] += w00*h4.x + w01*h4.y + w02*h4.z + w03*h4.w;
        acc1[w] += w10*h4.x + w11*h4.y + w12*h4.z + w13*h4.w;
      }
    }
#pragma unroll
    for (int w=0; w<16; w++){ gsh[g0][w] = acc0[w]; gsh[g1][w] = acc1[w]; }
    __syncthreads();                                        // (G)

    float hnew[8];
#pragma unroll
    for (int u=0; u<8; u++){
      int j = ujg*8 + u;
      float gi = sigmoid_f(gsh[j][uw]);
      float gf = sigmoid_f(gsh[HC + j][uw]);
      float gg = tanh_f   (gsh[2*HC + j][uw]);
      float go = sigmoid_f(gsh[3*HC + j][uw]);
      c[u] = gf*c[u] + gi*gg;
      hnew[u] = go * tanh_f(c[u]);
    }
#pragma unroll
    for (int u=0; u<8; u+=4)
      *(float4*)&h_sh[uw][ujg*8 + u] = make_float4(hnew[u],hnew[u+1],hnew[u+2],hnew[u+3]);
    if (t == lw-1){
#pragma unroll
      for (int u=0; u<8; u+=4)
        *(float4*)&embeds[(size_t)(s0+uw)*384 + ujg*8 + u]
            = make_float4(hnew[u],hnew[u+1],hnew[u+2],hnew[u+3]);
    }
  }
}

// ---------------------------------------------------------------- k_gather
__global__ __launch_bounds__(256) void k_gather(
    const int* __restrict__ sentence, const float* __restrict__ word_emb,
    float* __restrict__ embeds)
{
  int blk = blockIdx.x, tid = threadIdx.x;
  int s = blk*8 + (tid >> 5);
  int lane = tid & 31;
  int idx = sentence[s];
  const float4* src = (const float4*)(word_emb + (size_t)idx*DW);
  float4* dst = (float4*)(embeds + (size_t)s*384 + 128);
  dst[lane]      = src[lane];
  dst[lane + 32] = src[lane + 32];
}

// ---------------------------------------------------------------- k_pregate
// Output layout: pregates[dir][t][n], n = gate-major (PyTorch i,f,g,o blocks of 256)
__global__ __launch_bounds__(256) void k_pregate(
    const float* __restrict__ embeds,
    const float* __restrict__ Wih_fw, const float* __restrict__ b_fw,
    const float* __restrict__ Wih_bw, const float* __restrict__ b_bw,
    float* __restrict__ pregates)
{
  int dir = blockIdx.z;
  const float* W    = dir ? Wih_bw : Wih_fw;
  const float* bias = dir ? b_bw   : b_fw;
  int t0 = blockIdx.x*64, n0 = blockIdx.y*64;
  __shared__ float a_sh[16][68];
  __shared__ float b_sh[16][68];
  int tid = threadIdx.x;
  int li = tid & 63, kq = tid >> 6;
  int ti = tid >> 4, tj = tid & 15;
  float acc[4][4];
#pragma unroll
  for (int ii=0; ii<4; ii++)
#pragma unroll
    for (int jj=0; jj<4; jj++) acc[ii][jj] = 0.0f;

  for (int k0=0; k0<384; k0+=16){
    float4 av = *(const float4*)&embeds[(size_t)(t0+li)*384 + k0 + kq*4];
    float4 bv = *(const float4*)&W     [(size_t)(n0+li)*384 + k0 + kq*4];
    __syncthreads();
    a_sh[kq*4+0][li]=av.x; a_sh[kq*4+1][li]=av.y; a_sh[kq*4+2][li]=av.z; a_sh[kq*4+3][li]=av.w;
    b_sh[kq*4+0][li]=bv.x; b_sh[kq*4+1][li]=bv.y; b_sh[kq*4+2][li]=bv.z; b_sh[kq*4+3][li]=bv.w;
    __syncthreads();
#pragma unroll
    for (int kk=0; kk<16; kk++){
      float4 a4 = *(const float4*)&a_sh[kk][ti*4];
      float4 b4 = *(const float4*)&b_sh[kk][tj*4];
      float aa[4] = {a4.x,a4.y,a4.z,a4.w};
      float bb[4] = {b4.x,b4.y,b4.z,b4.w};
#pragma unroll
      for (int ii=0; ii<4; ii++)
#pragma unroll
        for (int jj=0; jj<4; jj++) acc[ii][jj] += aa[ii]*bb[jj];
    }
  }
  float4 bias4 = *(const float4*)&bias[n0 + tj*4];
  float bb2[4] = {bias4.x,bias4.y,bias4.z,bias4.w};
#pragma unroll
  for (int ii=0; ii<4; ii++){
    float4 o = make_float4(acc[ii][0]+bb2[0], acc[ii][1]+bb2[1],
                           acc[ii][2]+bb2[2], acc[ii][3]+bb2[3]);
    *(float4*)&pregates[((size_t)dir*S_LEN + (t0+ti*4+ii))*NG + n0 + tj*4] = o;
  }
}

// ---------------------------------------------------------------- k_recurrent
// 64 blocks; workers b%8==0 (fw) / b%8==1 (bw), slice g=b>>3 owns units [32g,32g+32).
// Thread (r4=tid>>3, ke=tid&7): 4 gate rows x 32-k slice of Whh in VGPRs (hoistable now
// that hbuf is __restrict__). Wave 0 lanes 0..31: activations + tagged store.
// Wave 1: polls all 256 tagged slots, fills h_sh. 2 barriers/step.
__global__ __launch_bounds__(256, 1) void k_recurrent(
    const float* __restrict__ Whh_fw, const float* __restrict__ Whh_bw,
    const float* __restrict__ pregates,
    unsigned long long* __restrict__ hbuf,
    float* __restrict__ hout)
{
  int b = blockIdx.x;
  if ((b & 7) > 1) return;
  int dir = b & 7, g = b >> 3;
  int tid = threadIdx.x;
  const float* Whh = dir ? Whh_bw : Whh_fw;
  const float* pgb = pregates + (size_t)dir * S_LEN * NG;
  unsigned long long* __restrict__ hb = hbuf + (size_t)dir * 2 * H2;

  __shared__ float h_sh[8*36];        // padded: ph(k)=(k>>5)*36+(k&31)
  __shared__ float gacc[128];

  int r4 = tid >> 3, ke = tid & 7;
  int q   = r4 >> 3;                  // gate block 0..3 (i,f,g,o)
  int jj4 = (4*r4) & 31;
  int row0 = q*H2 + g*32 + jj4;

  float w[4][32];
#pragma unroll
  for (int rr=0; rr<4; rr++){
    const float* wr = Whh + (size_t)(row0+rr)*H2 + ke*32;
#pragma unroll
    for (int kq=0; kq<8; kq++){
      float4 v = *(const float4*)&wr[kq*4];
      w[rr][kq*4+0]=v.x; w[rr][kq*4+1]=v.y; w[rr][kq*4+2]=v.z; w[rr][kq*4+3]=v.w;
    }
  }
  float c = 0.0f;
  h_sh[(tid>>5)*36 + (tid&31)] = 0.0f;
  __syncthreads();

  float4 pgn = make_float4(0.f,0.f,0.f,0.f);
  {
    int t0 = dir ? (S_LEN-1) : 0;
    if (ke == 0) pgn = *(const float4*)&pgb[(size_t)t0*NG + row0];
  }

  for (int sstep=0; sstep<S_LEN; sstep++){
    float4 pg = pgn;
    if (ke == 0 && sstep+1 < S_LEN){
      int tn = dir ? (S_LEN-2-sstep) : (sstep+1);
      pgn = *(const float4*)&pgb[(size_t)tn*NG + row0];
    }

    float a0=0.f, a1=0.f, a2=0.f, a3=0.f;
    const float* hk = &h_sh[ke*36];
#pragma unroll
    for (int kq=0; kq<8; kq++){
      float4 h4 = *(const float4*)&hk[kq*4];
      a0 += w[0][kq*4+0]*h4.x + w[0][kq*4+1]*h4.y + w[0][kq*4+2]*h4.z + w[0][kq*4+3]*h4.w;
      a1 += w[1][kq*4+0]*h4.x + w[1][kq*4+1]*h4.y + w[1][kq*4+2]*h4.z + w[1][kq*4+3]*h4.w;
      a2 += w[2][kq*4+0]*h4.x + w[2][kq*4+1]*h4.y + w[2][kq*4+2]*h4.z + w[2][kq*4+3]*h4.w;
      a3 += w[3][kq*4+0]*h4.x + w[3][kq*4+1]*h4.y + w[3][kq*4+2]*h4.z + w[3][kq*4+3]*h4.w;
    }
    a0 += __shfl_xor(a0,1); a1 += __shfl_xor(a1,1); a2 += __shfl_xor(a2,1); a3 += __shfl_xor(a3,1);
    a0 += __shfl_xor(a0,2); a1 += __shfl_xor(a1,2); a2 += __shfl_xor(a2,2); a3 += __shfl_xor(a3,2);
    a0 += __shfl_xor(a0,4); a1 += __shfl_xor(a1,4); a2 += __shfl_xor(a2,4); a3 += __shfl_xor(a3,4);
    if (ke == 0)
      *(float4*)&gacc[r4*4] = make_float4(a0+pg.x, a1+pg.y, a2+pg.z, a3+pg.w);
    __syncthreads();                                        // (1)

    if (tid < 32){
      // producer: activations + tagged store (critical path)
      int t = dir ? (S_LEN-1-sstep) : sstep;
      float gi = sigmoid_f(gacc[tid]);
      float gf = sigmoid_f(gacc[32+tid]);
      float gg = tanh_f  (gacc[64+tid]);
      float go = sigmoid_f(gacc[96+tid]);
      c = gf*c + gi*gg;
      float hn = go * tanh_f(c);
      unsigned long long pack =
          ((unsigned long long)__float_as_uint(hn) << 32) | (unsigned long long)(unsigned)(sstep+1);
      __hip_atomic_store(&hb[(sstep&1)*H2 + g*32 + tid], pack,
                         __ATOMIC_RELAXED, __HIP_MEMORY_SCOPE_AGENT);
      hout[(size_t)t*512 + dir*H2 + g*32 + tid] = hn;
    } else if (tid >= 64 && tid < 128){
      // consumer wave: starts polling remote slices while wave 0 does activations
      int lane = tid - 64;
      unsigned tag = (unsigned)(sstep+1);
      unsigned long long* __restrict__ base = &hb[(sstep&1)*H2];
      unsigned long long v0,v1,v2,v3;
      for (;;){
        v0 = __hip_atomic_load(base+lane,     __ATOMIC_RELAXED, __HIP_MEMORY_SCOPE_AGENT);
        v1 = __hip_atomic_load(base+lane+64,  __ATOMIC_RELAXED, __HIP_MEMORY_SCOPE_AGENT);
        v2 = __hip_atomic_load(base+lane+128, __ATOMIC_RELAXED, __HIP_MEMORY_SCOPE_AGENT);
        v3 = __hip_atomic_load(base+lane+192, __ATOMIC_RELAXED, __HIP_MEMORY_SCOPE_AGENT);
        if ( ((unsigned)v0==tag) & ((unsigned)v1==tag) &
             ((unsigned)v2==tag) & ((unsigned)v3==tag) ) break;
      }
      h_sh[((lane    )>>5)*36 + ((lane    )&31)] = __uint_as_float((unsigned)(v0>>32));
      h_sh[((lane+ 64)>>5)*36 + ((lane+ 64)&31)] = __uint_as_float((unsigned)(v1>>32));
      h_sh[((lane+128)>>5)*36 + ((lane+128)&31)] = __uint_as_float((unsigned)(v2>>32));
      h_sh[((lane+192)>>5)*36 + ((lane+192)&31)] = __uint_as_float((unsigned)(v3>>32));
    }
    __syncthreads();                                        // (2)
  }
}

// ---------------------------------------------------------------- k_output
__global__ __launch_bounds__(256) void k_output(
    const float* __restrict__ hout, const float* __restrict__ outW,
    const float* __restrict__ outb, float* __restrict__ out)
{
  __shared__ float wT[128][66];
  __shared__ float hsh[32][132];
  __shared__ float lsh[32][66];
  __shared__ float msh[32][2];
  int t0 = blockIdx.x*32, tid = threadIdx.x;
  int n  = tid & 63, tg = tid >> 6;
  int sl = tid >> 3, kg = tid & 7;
  int wn = tid & 63, wk = tid >> 6;
  float acc[8];
#pragma unroll
  for (int u=0; u<8; u++) acc[u] = 0.0f;

  for (int kc=0; kc<4; kc++){
    int k0 = kc*128;
    float4 wreg[8];
#pragma unroll
    for (int e=0; e<8; e++) wreg[e] = *(const float4*)&outW[(size_t)wn*512 + k0 + wk*32 + e*4];
    float4 hreg[4];
#pragma unroll
    for (int e=0; e<4; e++) hreg[e] = *(const float4*)&hout[(size_t)(t0+sl)*512 + k0 + kg*16 + e*4];
    __syncthreads();
#pragma unroll
    for (int e=0; e<8; e++){
      int kk = wk*32 + e*4;
      wT[kk+0][wn]=wreg[e].x; wT[kk+1][wn]=wreg[e].y; wT[kk+2][wn]=wreg[e].z; wT[kk+3][wn]=wreg[e].w;
    }
#pragma unroll
    for (int e=0; e<4; e++) *(float4*)&hsh[sl][kg*16 + e*4] = hreg[e];
    __syncthreads();
#pragma unroll
    for (int kk4=0; kk4<128; kk4+=4){
      float w0 = wT[kk4+0][n], w1 = wT[kk4+1][n], w2 = wT[kk4+2][n], w3 = wT[kk4+3][n];
#pragma unroll
      for (int u=0; u<8; u++){
        float4 h4 = *(const float4*)&hsh[tg*8+u][kk4];
        acc[u] += w0*h4.x + w1*h4.y + w2*h4.z + w3*h4.w;
      }
    }
  }
  float bn = outb[n];
#pragma unroll
  for (int u=0; u<8; u++) lsh[tg*8+u][n] = acc[u] + bn;
  __syncthreads();
  if (tid < 32){
    float M = -3.4e38f;
    for (int j=0; j<NTAG; j++) M = fmaxf(M, lsh[tid][j]);
    float ssum = 0.0f;
    for (int j=0; j<NTAG; j++) ssum += expf(lsh[tid][j] - M);
    msh[tid][0] = M; msh[tid][1] = logf(ssum);
  }
  __syncthreads();
#pragma unroll
  for (int u=0; u<8; u++){
    int tt = tg*8+u;
    out[(size_t)(t0+tt)*NTAG + n] = lsh[tt][n] - msh[tt][0] - msh[tt][1];
  }
}

// ---------------------------------------------------------------- launch
extern "C" void kernel_launch(void* const* d_in, const int* in_sizes, int n_in,
                              void* d_out, int out_size, void* d_ws, size_t ws_size,
                              hipStream_t stream)
{
  (void)in_sizes; (void)n_in; (void)out_size; (void)ws_size;
  const int*   sentence = (const int*)d_in[0];
  const int*   charsets = (const int*)d_in[1];
  const int*   char_len = (const int*)d_in[2];
  const float* word_emb = (const float*)d_in[3];
  const float* char_emb = (const float*)d_in[4];
  const float* char_Wih = (const float*)d_in[5];
  const float* char_Whh = (const float*)d_in[6];
  const float* char_b   = (const float*)d_in[7];
  const float* fw_Wih   = (const float*)d_in[8];
  const float* fw_Whh   = (const float*)d_in[9];
  const float* fw_b     = (const float*)d_in[10];
  const float* bw_Wih   = (const float*)d_in[11];
  const float* bw_Whh   = (const float*)d_in[12];
  const float* bw_b     = (const float*)d_in[13];
  const float* out_W    = (const float*)d_in[14];
  const float* out_b    = (const float*)d_in[15];
  float* out = (float*)d_out;

  char* ws = (char*)d_ws;
  float* preC     = (float*)(ws);
  float* whhTc    = (float*)(ws + 262144);
  float* embeds   = (float*)(ws + 524288);
  float* pregates = (float*)(ws + 13107200);
  float* houtb    = (float*)(ws + 80216064);
  unsigned long long* hbuf = (unsigned long long*)(ws + 96993280);

  k_prep     <<<256,  512, 0, stream>>>(char_emb, char_Wih, char_Whh, char_b, preC, whhTc);
  k_char_lstm<<<512,  256, 0, stream>>>(charsets, char_len, preC, whhTc, embeds);
  k_gather   <<<1024, 256, 0, stream>>>(sentence, word_emb, embeds);
  k_pregate  <<<dim3(128,16,2), 256, 0, stream>>>(embeds, fw_Wih, fw_b, bw_Wih, bw_b, pregates);
  k_recurrent<<<64,   256, 0, stream>>>(fw_Whh, bw_Whh, pregates, hbuf, houtb);
  k_output   <<<256,  256, 0, stream>>>(houtb, out_W, out_b, out);
}